// Round 1
// baseline (470.946 us; speedup 1.0000x reference)
//
#include <hip/hip_runtime.h>
#include <hip/hip_bf16.h>
#include <stdint.h>

#define B_   8
#define N_   8192
#define C_   512
#define NB   256   // blocks per sequence (N_/32)
#define WIN  64

typedef __attribute__((ext_vector_type(8))) short short8;
typedef __attribute__((ext_vector_type(4))) float f32x4;
typedef __hip_bfloat16 bf16;

__device__ __forceinline__ void gload_lds16(const void* g, void* l) {
  __builtin_amdgcn_global_load_lds((const __attribute__((address_space(1))) void*)g,
                                   (__attribute__((address_space(3))) void*)l, 16, 0, 0);
}

__device__ __forceinline__ f32x4 mfma16(short8 a, short8 b, f32x4 c) {
  return __builtin_amdgcn_mfma_f32_16x16x32_bf16(a, b, c, 0, 0, 0);
}

// ---------------- conversion kernels ----------------

__global__ __launch_bounds__(256) void k_conv_x(const float4* __restrict__ x,
                                                ushort4* __restrict__ xb) {
  size_t idx = (size_t)blockIdx.x * 256 + threadIdx.x;   // one float4 each
  float4 v = x[idx];
  union { ushort4 u; bf16 b[4]; } o;
  o.b[0] = __float2bfloat16(v.x); o.b[1] = __float2bfloat16(v.y);
  o.b[2] = __float2bfloat16(v.z); o.b[3] = __float2bfloat16(v.w);
  xb[idx] = o.u;
}

// W_qkv (512 x 1536 row-major) -> Wt[o][k] with head-interleave permutation,
// so GEMM output col o in [0,512)=q, [512,1024)=k, [1024,1536)=v, channel o&511.
__global__ __launch_bounds__(256) void k_conv_wqkv(const float* __restrict__ W,
                                                   const float* __restrict__ bq,
                                                   bf16* __restrict__ Wt,
                                                   float* __restrict__ bperm) {
  int o = blockIdx.x;            // 0..1535
  int part = o >> 9;             // 0=q 1=k 2=v
  int c = o & 511;
  int h = c >> 6, d = c & 63;
  int src = h * 192 + part * 64 + d;
  for (int kk = threadIdx.x; kk < 512; kk += 256)
    Wt[(size_t)o * 512 + kk] = __float2bfloat16(W[(size_t)kk * 1536 + src]);
  if (threadIdx.x == 0) bperm[o] = bq[src];
}

__global__ __launch_bounds__(256) void k_conv_wproj(const float* __restrict__ W,
                                                    bf16* __restrict__ Wt) {
  int o = blockIdx.x;            // 0..511
  for (int kk = threadIdx.x; kk < 512; kk += 256)
    Wt[(size_t)o * 512 + kk] = __float2bfloat16(W[(size_t)kk * 512 + o]);
}

// ---------------- GEMM: C[M x Ncols] = A[M x 512] * Bt[Ncols x 512]^T + bias ----------------
// EPI 0: qkv epilogue (bf16 scatter to q/k/v in [b][s][blk][c] layout)
// EPI 1: proj epilogue (f32 row-major out)
template <int EPI>
__global__ __launch_bounds__(256) void k_gemm(const bf16* __restrict__ A,
                                              const bf16* __restrict__ Bt,
                                              const float* __restrict__ bias,
                                              bf16* __restrict__ qb,
                                              bf16* __restrict__ kb,
                                              bf16* __restrict__ vb,
                                              float* __restrict__ outf) {
  __shared__ bf16 As[128 * 64];
  __shared__ bf16 Bs[128 * 64];
  const int tid = threadIdx.x;
  const int lane = tid & 63, wid = tid >> 6;
  const int wr = wid >> 1, wc = wid & 1;
  const int l15 = lane & 15, l4 = lane >> 4;
  const size_t m0 = (size_t)blockIdx.x * 128;
  const int n0 = blockIdx.y * 128;
  const int K = 512;

  f32x4 acc[4][4];
#pragma unroll
  for (int fi = 0; fi < 4; ++fi)
#pragma unroll
    for (int fj = 0; fj < 4; ++fj) acc[fi][fj] = (f32x4){0.f, 0.f, 0.f, 0.f};

#define STAGE(k0)                                                              \
  {                                                                            \
    _Pragma("unroll") for (int i = 0; i < 4; ++i) {                            \
      int li = i * 256 + tid;                                                  \
      int row = li >> 3, ch = li & 7;                                          \
      gload_lds16(A + (m0 + row) * K + (k0) + ch * 8, (char*)As + li * 16);    \
      gload_lds16(Bt + (size_t)(n0 + row) * K + (k0) + ch * 8,                 \
                  (char*)Bs + li * 16);                                        \
    }                                                                          \
  }

  STAGE(0);
  for (int ks = 0; ks < 8; ++ks) {
    __syncthreads();   // drains vmcnt(0): staged tile ready
#pragma unroll
    for (int half = 0; half < 2; ++half) {
      short8 a[4], b[4];
#pragma unroll
      for (int f = 0; f < 4; ++f) {
        a[f] = *(const short8*)&As[(wr * 64 + f * 16 + l15) * 64 + half * 32 + l4 * 8];
        b[f] = *(const short8*)&Bs[(wc * 64 + f * 16 + l15) * 64 + half * 32 + l4 * 8];
      }
#pragma unroll
      for (int fi = 0; fi < 4; ++fi)
#pragma unroll
        for (int fj = 0; fj < 4; ++fj)
          acc[fi][fj] = mfma16(a[fi], b[fj], acc[fi][fj]);
    }
    if (ks < 7) {
      __syncthreads();
      STAGE((ks + 1) * 64);
    }
  }

  if (EPI == 0) {
#pragma unroll
    for (int fi = 0; fi < 4; ++fi)
#pragma unroll
      for (int fj = 0; fj < 4; ++fj) {
        int o = n0 + wc * 64 + fj * 16 + l15;
        float bia = bias[o];
        int part = o >> 9;
        int c = o & 511;
        bf16* dst = part == 0 ? qb : (part == 1 ? kb : vb);
#pragma unroll
        for (int r = 0; r < 4; ++r) {
          size_t m = m0 + wr * 64 + fi * 16 + l4 * 4 + r;
          int bidx = (int)(m >> 13);
          int n = (int)(m & 8191);
          int blk = n >> 5, s = n & 31;
          size_t di = (((size_t)(bidx * 32 + s) * 256 + blk) << 9) | c;
          dst[di] = __float2bfloat16(acc[fi][fj][r] + bia);
        }
      }
  } else {
#pragma unroll
    for (int fi = 0; fi < 4; ++fi)
#pragma unroll
      for (int fj = 0; fj < 4; ++fj) {
        int o = n0 + wc * 64 + fj * 16 + l15;
        float bia = bias[o];
#pragma unroll
        for (int r = 0; r < 4; ++r) {
          size_t m = m0 + wr * 64 + fi * 16 + l4 * 4 + r;
          outf[m * 512 + o] = acc[fi][fj][r] + bia;
        }
      }
  }
#undef STAGE
}

// ---------------- v transpose: v[b][s][j][c] -> vT[b][s][c][j] ----------------
__global__ __launch_bounds__(256) void k_transpose_v(const bf16* __restrict__ v,
                                                     bf16* __restrict__ vT) {
  __shared__ bf16 t[32][36];
  int bs = blockIdx.x, j0 = blockIdx.y * 32, c0 = blockIdx.z * 32;
  const bf16* src = v + (size_t)bs * NB * C_;
  bf16* dst = vT + (size_t)bs * C_ * NB;
  int r = threadIdx.x >> 3, c4 = (threadIdx.x & 7) * 4;
  *(ushort4*)&t[r][c4] = *(const ushort4*)(src + (size_t)(j0 + r) * C_ + c0 + c4);
  __syncthreads();
  union { ushort4 u; bf16 b[4]; } o;
  o.b[0] = t[c4 + 0][r]; o.b[1] = t[c4 + 1][r];
  o.b[2] = t[c4 + 2][r]; o.b[3] = t[c4 + 3][r];
  *(ushort4*)(dst + (size_t)(c0 + r) * NB + j0 + c4) = o.u;
}

// ---------------- banded block attention ----------------
// grid: (B_*32, 8).  One wg = 32 query blocks for one (b,s).
__global__ __launch_bounds__(256) void k_attn(const bf16* __restrict__ qg,
                                              const bf16* __restrict__ kg,
                                              const bf16* __restrict__ vTg,
                                              bf16* __restrict__ outb) {
  __shared__ bf16 Qs[32][520];    // padded: 1040B rows -> 2-way banks only
  __shared__ float Ss[32][164];
  __shared__ bf16 Ps[32][168];
  __shared__ float rowsum[32];
  const int tid = threadIdx.x, lane = tid & 63, wid = tid >> 6;
  const int l15 = lane & 15, l4 = lane >> 4;
  const int bs = blockIdx.x;
  const int b = bs >> 5, s = bs & 31;
  const int i0 = blockIdx.y * 32;
  const int jlo = max(0, i0 - WIN);
  const int jhi = min(NB - 1, i0 + 31 + WIN);
  const int L = jhi - jlo + 1;
  const int nch16 = (L + 15) >> 4, L16 = nch16 << 4;
  const int nch32 = (L16 + 31) >> 5, L32 = nch32 << 5;
  const bf16* Qb = qg + (size_t)bs * NB * C_;
  const bf16* Kb = kg + (size_t)bs * NB * C_;
  const bf16* Vb = vTg + (size_t)bs * C_ * NB;

  // stage Q (32 x 512)
#pragma unroll
  for (int qq = 0; qq < 8; ++qq) {
    int li = qq * 256 + tid;
    int row = li >> 6, ch = li & 63;
    *(float4*)&Qs[row][ch * 8] = *(const float4*)(Qb + (size_t)(i0 + row) * C_ + ch * 8);
  }
  __syncthreads();

  // phase 1: S = scale * Q K^T over the j band
  for (int jc = wid; jc < nch16; jc += 4) {
    f32x4 acc0 = (f32x4){0.f, 0.f, 0.f, 0.f};
    f32x4 acc1 = acc0;
    int jg = jlo + jc * 16 + l15;
    int jcl = min(jg, NB - 1);                 // clamp; masked later
    const bf16* kp = Kb + (size_t)jcl * C_ + l4 * 8;
    const bf16* q0 = &Qs[l15][l4 * 8];
    const bf16* q1 = &Qs[16 + l15][l4 * 8];
#pragma unroll
    for (int cc = 0; cc < 16; ++cc) {
      short8 bfr = *(const short8*)(kp + cc * 32);
      short8 a0 = *(const short8*)(q0 + cc * 32);
      short8 a1 = *(const short8*)(q1 + cc * 32);
      acc0 = mfma16(a0, bfr, acc0);
      acc1 = mfma16(a1, bfr, acc1);
    }
#pragma unroll
    for (int r = 0; r < 4; ++r) {
      Ss[l4 * 4 + r][jc * 16 + l15] = acc0[r] * 0.125f;
      Ss[16 + l4 * 4 + r][jc * 16 + l15] = acc1[r] * 0.125f;
    }
  }
  __syncthreads();

  // phase 2: masked softmax per row (8 lanes per row)
  {
    int row = tid >> 3, u = tid & 7;
    int i = i0 + row;
    int vlo = max(i - WIN, 0), vhi = min(i + WIN, NB - 1);
    float m = -1e30f;
    for (int jj = u; jj < L16; jj += 8) {
      int jg = jlo + jj;
      if (jg >= vlo && jg <= vhi) m = fmaxf(m, Ss[row][jj]);
    }
    m = fmaxf(m, __shfl_xor(m, 1));
    m = fmaxf(m, __shfl_xor(m, 2));
    m = fmaxf(m, __shfl_xor(m, 4));
    float sum = 0.f;
    for (int jj = u; jj < L32; jj += 8) {
      float p = 0.f;
      int jg = jlo + jj;
      if (jj < L16 && jg >= vlo && jg <= vhi) p = __expf(Ss[row][jj] - m);
      sum += p;
      Ps[row][jj] = __float2bfloat16(p);   // unnormalized; pad region = 0
    }
    sum += __shfl_xor(sum, 1);
    sum += __shfl_xor(sum, 2);
    sum += __shfl_xor(sum, 4);
    if (u == 0) rowsum[row] = sum;
  }
  __syncthreads();

  // phase 3: O = (P/rowsum) V  ; wave owns 128 channels
  {
    const int c0 = wid * 128;
#pragma unroll
    for (int ic = 0; ic < 2; ++ic) {
#pragma unroll
      for (int f = 0; f < 8; ++f) {
        f32x4 acc = (f32x4){0.f, 0.f, 0.f, 0.f};
        int c = c0 + f * 16 + l15;
        const bf16* pr = &Ps[ic * 16 + l15][l4 * 8];
        for (int j32 = 0; j32 < nch32; ++j32) {
          int jg = jlo + j32 * 32 + l4 * 8;
          int jcl = (jg <= NB - 8) ? jg : 0;   // whole 8-chunk OOB -> P=0 covers
          short8 a = *(const short8*)(pr + j32 * 32);
          short8 bfr = *(const short8*)(Vb + (size_t)c * NB + jcl);
          acc = mfma16(a, bfr, acc);
        }
#pragma unroll
        for (int r = 0; r < 4; ++r) {
          int il = ic * 16 + l4 * 4 + r;
          float val = acc[r] / rowsum[il];
          int n = (i0 + il) * 32 + s;
          outb[((size_t)b * N_ + n) * C_ + c] = __float2bfloat16(val);
        }
      }
    }
  }
}

// ---------------- launch ----------------
extern "C" void kernel_launch(void* const* d_in, const int* in_sizes, int n_in,
                              void* d_out, int out_size, void* d_ws, size_t ws_size,
                              hipStream_t stream) {
  const float* x = (const float*)d_in[0];
  const float* Wqkv = (const float*)d_in[1];
  const float* bqkv = (const float*)d_in[2];
  const float* Wproj = (const float*)d_in[3];
  const float* bproj = (const float*)d_in[4];

  char* ws = (char*)d_ws;
  const size_t SLOT = 67108864ull;           // 64 MiB (33.5M bf16)
  bf16* slotA = (bf16*)ws;                   // xb, then vT
  bf16* slotB = (bf16*)(ws + SLOT);          // v, then attn_out
  bf16* Wqkv_t = (bf16*)(ws + 2 * SLOT);
  bf16* Wproj_t = (bf16*)(ws + 2 * SLOT + 1572864);
  float* bias_perm = (float*)(ws + 2 * SLOT + 1572864 + 524288);
  bf16* qbuf = (bf16*)d_out;                 // q,k scratch inside d_out (dead before proj writes)
  bf16* kbuf = qbuf + 33554432ull;

  k_conv_x<<<32768, 256, 0, stream>>>((const float4*)x, (ushort4*)slotA);
  k_conv_wqkv<<<1536, 256, 0, stream>>>(Wqkv, bqkv, Wqkv_t, bias_perm);
  k_conv_wproj<<<512, 256, 0, stream>>>(Wproj, Wproj_t);

  // qkv projection: A=xb, Bt=Wqkv_t -> q,k (d_out), v (slotB)
  k_gemm<0><<<dim3(512, 12), 256, 0, stream>>>(slotA, Wqkv_t, bias_perm,
                                               qbuf, kbuf, slotB, nullptr);
  // v -> vT (slotA; xb dead)
  k_transpose_v<<<dim3(256, 8, 16), 256, 0, stream>>>(slotB, slotA);
  // attention -> attn_out (slotB; v dead)
  k_attn<<<dim3(256, 8), 256, 0, stream>>>(qbuf, kbuf, slotA, slotB);
  // proj: A=attn_out, Bt=Wproj_t -> d_out f32 (q,k dead)
  k_gemm<1><<<dim3(512, 4), 256, 0, stream>>>(slotB, Wproj_t, bproj,
                                              nullptr, nullptr, nullptr, (float*)d_out);
}

// Round 2
// 439.956 us; speedup vs baseline: 1.0704x; 1.0704x over previous
//
#include <hip/hip_runtime.h>
#include <hip/hip_bf16.h>
#include <stdint.h>

#define B_   8
#define N_   8192
#define C_   512
#define NB   256   // blocks per sequence (N_/32)
#define WIN  64

typedef __attribute__((ext_vector_type(8))) short short8;
typedef __attribute__((ext_vector_type(4))) float f32x4;
typedef __hip_bfloat16 bf16;

__device__ __forceinline__ void gload_lds16(const void* g, void* l) {
  __builtin_amdgcn_global_load_lds((const __attribute__((address_space(1))) void*)g,
                                   (__attribute__((address_space(3))) void*)l, 16, 0, 0);
}

__device__ __forceinline__ f32x4 mfma16(short8 a, short8 b, f32x4 c) {
  return __builtin_amdgcn_mfma_f32_16x16x32_bf16(a, b, c, 0, 0, 0);
}

// ---------------- conversion kernels ----------------

__global__ __launch_bounds__(256) void k_conv_x(const float4* __restrict__ x,
                                                ushort4* __restrict__ xb) {
  size_t idx = (size_t)blockIdx.x * 256 + threadIdx.x;   // one float4 each
  float4 v = x[idx];
  union { ushort4 u; bf16 b[4]; } o;
  o.b[0] = __float2bfloat16(v.x); o.b[1] = __float2bfloat16(v.y);
  o.b[2] = __float2bfloat16(v.z); o.b[3] = __float2bfloat16(v.w);
  xb[idx] = o.u;
}

// W_qkv (512 x 1536 row-major) -> Wt[o][k] with head-interleave permutation,
// so GEMM output col o in [0,512)=q, [512,1024)=k, [1024,1536)=v, channel o&511.
__global__ __launch_bounds__(256) void k_conv_wqkv(const float* __restrict__ W,
                                                   const float* __restrict__ bq,
                                                   bf16* __restrict__ Wt,
                                                   float* __restrict__ bperm) {
  int o = blockIdx.x;            // 0..1535
  int part = o >> 9;             // 0=q 1=k 2=v
  int c = o & 511;
  int h = c >> 6, d = c & 63;
  int src = h * 192 + part * 64 + d;
  for (int kk = threadIdx.x; kk < 512; kk += 256)
    Wt[(size_t)o * 512 + kk] = __float2bfloat16(W[(size_t)kk * 1536 + src]);
  if (threadIdx.x == 0) bperm[o] = bq[src];
}

__global__ __launch_bounds__(256) void k_conv_wproj(const float* __restrict__ W,
                                                    bf16* __restrict__ Wt) {
  int o = blockIdx.x;            // 0..511
  for (int kk = threadIdx.x; kk < 512; kk += 256)
    Wt[(size_t)o * 512 + kk] = __float2bfloat16(W[(size_t)kk * 512 + o]);
}

// ---------------- GEMM: C[M x Ncols] = A[M x 512] * Bt[Ncols x 512]^T + bias ----------------
// 1D grid = (M/128)*NT blocks; bijective XCD-chunk swizzle then nt-fastest
// decomposition so the NT n-tiles sharing an A panel are consecutive on one XCD.
// LDS XOR swizzle (T2): linear global_load_lds dest, inverse-swizzled global
// source column, swizzled ds_read slot -> 16-way bank conflict becomes 2-way.
// EPI 0: qkv epilogue (bf16 scatter to q/k/v in [b][s][blk][c] layout)
// EPI 1: proj epilogue (f32 row-major out)
template <int EPI>
__global__ __launch_bounds__(256) void k_gemm(const bf16* __restrict__ A,
                                              const bf16* __restrict__ Bt,
                                              const float* __restrict__ bias,
                                              bf16* __restrict__ qb,
                                              bf16* __restrict__ kb,
                                              bf16* __restrict__ vb,
                                              float* __restrict__ outf,
                                              int NT) {
  __shared__ bf16 As[128 * 64];
  __shared__ bf16 Bs[128 * 64];
  const int tid = threadIdx.x;
  const int lane = tid & 63, wid = tid >> 6;
  const int wr = wid >> 1, wc = wid & 1;
  const int l15 = lane & 15, l4 = lane >> 4;

  // XCD-chunk swizzle (grid % 8 == 0 guaranteed by launch) + nt-fastest split
  const int nwg = gridDim.x;
  const int cpx = nwg >> 3;
  const int swz = (blockIdx.x & 7) * cpx + (blockIdx.x >> 3);
  const int mt = swz / NT, nt = swz % NT;
  const size_t m0 = (size_t)mt * 128;
  const int n0 = nt * 128;
  const int K = 512;

  f32x4 acc[4][4];
#pragma unroll
  for (int fi = 0; fi < 4; ++fi)
#pragma unroll
    for (int fj = 0; fj < 4; ++fj) acc[fi][fj] = (f32x4){0.f, 0.f, 0.f, 0.f};

#define STAGE(k0)                                                              \
  {                                                                            \
    _Pragma("unroll") for (int i = 0; i < 4; ++i) {                            \
      int li = i * 256 + tid;                                                  \
      int row = li >> 3, ch = li & 7;                                          \
      int chs = ch ^ (row & 7);                                                \
      gload_lds16(A + (m0 + row) * K + (k0) + chs * 8, (char*)As + li * 16);   \
      gload_lds16(Bt + (size_t)(n0 + row) * K + (k0) + chs * 8,                \
                  (char*)Bs + li * 16);                                        \
    }                                                                          \
  }

  STAGE(0);
  for (int ks = 0; ks < 8; ++ks) {
    __syncthreads();   // drains vmcnt(0): staged tile ready
#pragma unroll
    for (int half = 0; half < 2; ++half) {
      short8 a[4], b[4];
#pragma unroll
      for (int f = 0; f < 4; ++f) {
        int ra = wr * 64 + f * 16 + l15;
        int rb = wc * 64 + f * 16 + l15;
        int sa = (half * 4 + l4) ^ (ra & 7);
        int sb = (half * 4 + l4) ^ (rb & 7);
        a[f] = *(const short8*)&As[ra * 64 + sa * 8];
        b[f] = *(const short8*)&Bs[rb * 64 + sb * 8];
      }
#pragma unroll
      for (int fi = 0; fi < 4; ++fi)
#pragma unroll
        for (int fj = 0; fj < 4; ++fj)
          acc[fi][fj] = mfma16(a[fi], b[fj], acc[fi][fj]);
    }
    if (ks < 7) {
      __syncthreads();
      STAGE((ks + 1) * 64);
    }
  }

  if (EPI == 0) {
#pragma unroll
    for (int fi = 0; fi < 4; ++fi)
#pragma unroll
      for (int fj = 0; fj < 4; ++fj) {
        int o = n0 + wc * 64 + fj * 16 + l15;
        float bia = bias[o];
        int part = o >> 9;
        int c = o & 511;
        bf16* dst = part == 0 ? qb : (part == 1 ? kb : vb);
#pragma unroll
        for (int r = 0; r < 4; ++r) {
          size_t m = m0 + wr * 64 + fi * 16 + l4 * 4 + r;
          int bidx = (int)(m >> 13);
          int n = (int)(m & 8191);
          int blk = n >> 5, s = n & 31;
          size_t di = (((size_t)(bidx * 32 + s) * 256 + blk) << 9) | c;
          dst[di] = __float2bfloat16(acc[fi][fj][r] + bia);
        }
      }
  } else {
#pragma unroll
    for (int fi = 0; fi < 4; ++fi)
#pragma unroll
      for (int fj = 0; fj < 4; ++fj) {
        int o = n0 + wc * 64 + fj * 16 + l15;
        float bia = bias[o];
#pragma unroll
        for (int r = 0; r < 4; ++r) {
          size_t m = m0 + wr * 64 + fi * 16 + l4 * 4 + r;
          outf[m * 512 + o] = acc[fi][fj][r] + bia;
        }
      }
  }
#undef STAGE
}

// ---------------- v transpose: v[b][s][j][c] -> vT[b][s][c][j] ----------------
__global__ __launch_bounds__(256) void k_transpose_v(const bf16* __restrict__ v,
                                                     bf16* __restrict__ vT) {
  __shared__ bf16 t[32][36];
  int bs = blockIdx.x, j0 = blockIdx.y * 32, c0 = blockIdx.z * 32;
  const bf16* src = v + (size_t)bs * NB * C_;
  bf16* dst = vT + (size_t)bs * C_ * NB;
  int r = threadIdx.x >> 3, c4 = (threadIdx.x & 7) * 4;
  *(ushort4*)&t[r][c4] = *(const ushort4*)(src + (size_t)(j0 + r) * C_ + c0 + c4);
  __syncthreads();
  union { ushort4 u; bf16 b[4]; } o;
  o.b[0] = t[c4 + 0][r]; o.b[1] = t[c4 + 1][r];
  o.b[2] = t[c4 + 2][r]; o.b[3] = t[c4 + 3][r];
  *(ushort4*)(dst + (size_t)(c0 + r) * NB + j0 + c4) = o.u;
}

// ---------------- banded block attention ----------------
// grid: (B_*32, 8).  One wg = 32 query blocks for one (b,s).
__global__ __launch_bounds__(256) void k_attn(const bf16* __restrict__ qg,
                                              const bf16* __restrict__ kg,
                                              const bf16* __restrict__ vTg,
                                              bf16* __restrict__ outb) {
  __shared__ bf16 Qs[32][520];    // padded: 1040B rows -> 2-way banks only
  __shared__ float Ss[32][164];
  __shared__ bf16 Ps[32][168];
  __shared__ float rowsum[32];
  const int tid = threadIdx.x, lane = tid & 63, wid = tid >> 6;
  const int l15 = lane & 15, l4 = lane >> 4;
  const int bs = blockIdx.x;
  const int b = bs >> 5, s = bs & 31;
  const int i0 = blockIdx.y * 32;
  const int jlo = max(0, i0 - WIN);
  const int jhi = min(NB - 1, i0 + 31 + WIN);
  const int L = jhi - jlo + 1;
  const int nch16 = (L + 15) >> 4, L16 = nch16 << 4;
  const int nch32 = (L16 + 31) >> 5, L32 = nch32 << 5;
  const bf16* Qb = qg + (size_t)bs * NB * C_;
  const bf16* Kb = kg + (size_t)bs * NB * C_;
  const bf16* Vb = vTg + (size_t)bs * C_ * NB;

  // stage Q (32 x 512)
#pragma unroll
  for (int qq = 0; qq < 8; ++qq) {
    int li = qq * 256 + tid;
    int row = li >> 6, ch = li & 63;
    *(float4*)&Qs[row][ch * 8] = *(const float4*)(Qb + (size_t)(i0 + row) * C_ + ch * 8);
  }
  __syncthreads();

  // phase 1: S = scale * Q K^T over the j band
  for (int jc = wid; jc < nch16; jc += 4) {
    f32x4 acc0 = (f32x4){0.f, 0.f, 0.f, 0.f};
    f32x4 acc1 = acc0;
    int jg = jlo + jc * 16 + l15;
    int jcl = min(jg, NB - 1);                 // clamp; masked later
    const bf16* kp = Kb + (size_t)jcl * C_ + l4 * 8;
    const bf16* q0 = &Qs[l15][l4 * 8];
    const bf16* q1 = &Qs[16 + l15][l4 * 8];
#pragma unroll
    for (int cc = 0; cc < 16; ++cc) {
      short8 bfr = *(const short8*)(kp + cc * 32);
      short8 a0 = *(const short8*)(q0 + cc * 32);
      short8 a1 = *(const short8*)(q1 + cc * 32);
      acc0 = mfma16(a0, bfr, acc0);
      acc1 = mfma16(a1, bfr, acc1);
    }
#pragma unroll
    for (int r = 0; r < 4; ++r) {
      Ss[l4 * 4 + r][jc * 16 + l15] = acc0[r] * 0.125f;
      Ss[16 + l4 * 4 + r][jc * 16 + l15] = acc1[r] * 0.125f;
    }
  }
  __syncthreads();

  // phase 2: masked softmax per row (8 lanes per row)
  {
    int row = tid >> 3, u = tid & 7;
    int i = i0 + row;
    int vlo = max(i - WIN, 0), vhi = min(i + WIN, NB - 1);
    float m = -1e30f;
    for (int jj = u; jj < L16; jj += 8) {
      int jg = jlo + jj;
      if (jg >= vlo && jg <= vhi) m = fmaxf(m, Ss[row][jj]);
    }
    m = fmaxf(m, __shfl_xor(m, 1));
    m = fmaxf(m, __shfl_xor(m, 2));
    m = fmaxf(m, __shfl_xor(m, 4));
    float sum = 0.f;
    for (int jj = u; jj < L32; jj += 8) {
      float p = 0.f;
      int jg = jlo + jj;
      if (jj < L16 && jg >= vlo && jg <= vhi) p = __expf(Ss[row][jj] - m);
      sum += p;
      Ps[row][jj] = __float2bfloat16(p);   // unnormalized; pad region = 0
    }
    sum += __shfl_xor(sum, 1);
    sum += __shfl_xor(sum, 2);
    sum += __shfl_xor(sum, 4);
    if (u == 0) rowsum[row] = sum;
  }
  __syncthreads();

  // phase 3: O = (P/rowsum) V  ; wave owns 128 channels
  {
    const int c0 = wid * 128;
#pragma unroll
    for (int ic = 0; ic < 2; ++ic) {
#pragma unroll
      for (int f = 0; f < 8; ++f) {
        f32x4 acc = (f32x4){0.f, 0.f, 0.f, 0.f};
        int c = c0 + f * 16 + l15;
        const bf16* pr = &Ps[ic * 16 + l15][l4 * 8];
        for (int j32 = 0; j32 < nch32; ++j32) {
          int jg = jlo + j32 * 32 + l4 * 8;
          int jcl = (jg <= NB - 8) ? jg : 0;   // whole 8-chunk OOB -> P=0 covers
          short8 a = *(const short8*)(pr + j32 * 32);
          short8 bfr = *(const short8*)(Vb + (size_t)c * NB + jcl);
          acc = mfma16(a, bfr, acc);
        }
#pragma unroll
        for (int r = 0; r < 4; ++r) {
          int il = ic * 16 + l4 * 4 + r;
          float val = acc[r] / rowsum[il];
          int n = (i0 + il) * 32 + s;
          outb[((size_t)b * N_ + n) * C_ + c] = __float2bfloat16(val);
        }
      }
    }
  }
}

// ---------------- launch ----------------
extern "C" void kernel_launch(void* const* d_in, const int* in_sizes, int n_in,
                              void* d_out, int out_size, void* d_ws, size_t ws_size,
                              hipStream_t stream) {
  const float* x = (const float*)d_in[0];
  const float* Wqkv = (const float*)d_in[1];
  const float* bqkv = (const float*)d_in[2];
  const float* Wproj = (const float*)d_in[3];
  const float* bproj = (const float*)d_in[4];

  char* ws = (char*)d_ws;
  const size_t SLOT = 67108864ull;           // 64 MiB (33.5M bf16)
  bf16* slotA = (bf16*)ws;                   // xb, then vT
  bf16* slotB = (bf16*)(ws + SLOT);          // v, then attn_out
  bf16* Wqkv_t = (bf16*)(ws + 2 * SLOT);
  bf16* Wproj_t = (bf16*)(ws + 2 * SLOT + 1572864);
  float* bias_perm = (float*)(ws + 2 * SLOT + 1572864 + 524288);
  bf16* qbuf = (bf16*)d_out;                 // q,k scratch inside d_out (dead before proj writes)
  bf16* kbuf = qbuf + 33554432ull;

  k_conv_x<<<32768, 256, 0, stream>>>((const float4*)x, (ushort4*)slotA);
  k_conv_wqkv<<<1536, 256, 0, stream>>>(Wqkv, bqkv, Wqkv_t, bias_perm);
  k_conv_wproj<<<512, 256, 0, stream>>>(Wproj, Wproj_t);

  // qkv projection: A=xb, Bt=Wqkv_t -> q,k (d_out), v (slotB)
  k_gemm<0><<<512 * 12, 256, 0, stream>>>(slotA, Wqkv_t, bias_perm,
                                          qbuf, kbuf, slotB, nullptr, 12);
  // v -> vT (slotA; xb dead)
  k_transpose_v<<<dim3(256, 8, 16), 256, 0, stream>>>(slotB, slotA);
  // attention -> attn_out (slotB; v dead)
  k_attn<<<dim3(256, 8), 256, 0, stream>>>(qbuf, kbuf, slotA, slotB);
  // proj: A=attn_out, Bt=Wproj_t -> d_out f32 (q,k dead)
  k_gemm<1><<<512 * 4, 256, 0, stream>>>(slotB, Wproj_t, bproj,
                                         nullptr, nullptr, nullptr, (float*)d_out, 4);
}

// Round 3
// 386.560 us; speedup vs baseline: 1.2183x; 1.1381x over previous
//
#include <hip/hip_runtime.h>
#include <hip/hip_bf16.h>
#include <stdint.h>

#define B_   8
#define N_   8192
#define C_   512
#define NB   256   // blocks per sequence (N_/32)
#define WIN  64

typedef __attribute__((ext_vector_type(8))) short short8;
typedef __attribute__((ext_vector_type(4))) float f32x4;
typedef __hip_bfloat16 bf16;

__device__ __forceinline__ void gload_lds16(const void* g, void* l) {
  __builtin_amdgcn_global_load_lds((const __attribute__((address_space(1))) void*)g,
                                   (__attribute__((address_space(3))) void*)l, 16, 0, 0);
}

__device__ __forceinline__ f32x4 mfma16(short8 a, short8 b, f32x4 c) {
  return __builtin_amdgcn_mfma_f32_16x16x32_bf16(a, b, c, 0, 0, 0);
}

// ---------------- conversion kernels ----------------

__global__ __launch_bounds__(256) void k_conv_x(const float4* __restrict__ x,
                                                ushort4* __restrict__ xb) {
  size_t idx = (size_t)blockIdx.x * 256 + threadIdx.x;   // one float4 each
  float4 v = x[idx];
  union { ushort4 u; bf16 b[4]; } o;
  o.b[0] = __float2bfloat16(v.x); o.b[1] = __float2bfloat16(v.y);
  o.b[2] = __float2bfloat16(v.z); o.b[3] = __float2bfloat16(v.w);
  xb[idx] = o.u;
}

// W_qkv (512 x 1536 row-major) -> Wt[o][k] with head-interleave permutation,
// so GEMM output col o in [0,512)=q, [512,1024)=k, [1024,1536)=v, channel o&511.
__global__ __launch_bounds__(256) void k_conv_wqkv(const float* __restrict__ W,
                                                   const float* __restrict__ bq,
                                                   bf16* __restrict__ Wt,
                                                   float* __restrict__ bperm) {
  int o = blockIdx.x;            // 0..1535
  int part = o >> 9;             // 0=q 1=k 2=v
  int c = o & 511;
  int h = c >> 6, d = c & 63;
  int src = h * 192 + part * 64 + d;
  for (int kk = threadIdx.x; kk < 512; kk += 256)
    Wt[(size_t)o * 512 + kk] = __float2bfloat16(W[(size_t)kk * 1536 + src]);
  if (threadIdx.x == 0) bperm[o] = bq[src];
}

__global__ __launch_bounds__(256) void k_conv_wproj(const float* __restrict__ W,
                                                    bf16* __restrict__ Wt) {
  int o = blockIdx.x;            // 0..511
  for (int kk = threadIdx.x; kk < 512; kk += 256)
    Wt[(size_t)o * 512 + kk] = __float2bfloat16(W[(size_t)kk * 512 + o]);
}

// ---------------- GEMM: C[M x Ncols] = A[M x 512] * Bt[Ncols x 512]^T + bias --------
// 256x256 tile, BK=64, 8 waves (2M x 4N), per-wave 128x64 output.
// Double-buffered 128KB dynamic LDS; prefetch next K-tile BEFORE compute with
// counted s_waitcnt vmcnt(8) (loads stay in flight across barriers, T3+T4);
// raw s_barrier; T2 slot-XOR swizzle (verified 0 conflicts); setprio on MFMA.
// EPI 0: qkv epilogue (bf16 scatter to q/k/v in [b][s][blk][c] layout)
// EPI 1: proj epilogue (f32 row-major out)
template <int EPI>
__global__ __launch_bounds__(512, 2) void k_gemm(const bf16* __restrict__ A,
                                                 const bf16* __restrict__ Bt,
                                                 const float* __restrict__ bias,
                                                 bf16* __restrict__ qb,
                                                 bf16* __restrict__ kb,
                                                 bf16* __restrict__ vb,
                                                 float* __restrict__ outf,
                                                 int NT) {
  extern __shared__ bf16 sm[];   // slot s: A at s*32768, B at s*32768+16384
  const int tid = threadIdx.x;
  const int lane = tid & 63, wid = tid >> 6;
  const int wr = wid >> 2, wcn = wid & 3;
  const int l15 = lane & 15, l4 = lane >> 4;

  // bijective XCD-chunk swizzle (grid % 8 == 0) + nt-fastest split
  const int nwg = gridDim.x;
  const int cpx = nwg >> 3;
  const int swz = (blockIdx.x & 7) * cpx + (blockIdx.x >> 3);
  const int mt = swz / NT, nt = swz % NT;
  const size_t m0 = (size_t)mt * 256;
  const int n0 = nt * 256;

  f32x4 acc[8][4];
#pragma unroll
  for (int fi = 0; fi < 8; ++fi)
#pragma unroll
    for (int fj = 0; fj < 4; ++fj) acc[fi][fj] = (f32x4){0.f, 0.f, 0.f, 0.f};

#define STAGEG(slot, k0)                                                       \
  {                                                                            \
    bf16* Adst = sm + (slot) * 32768;                                          \
    bf16* Bdst = Adst + 16384;                                                 \
    _Pragma("unroll") for (int i = 0; i < 4; ++i) {                            \
      int li = i * 512 + tid;                                                  \
      int row = li >> 3, ch = li & 7;                                          \
      int chs = ch ^ (row & 7);                                                \
      gload_lds16(A + (m0 + row) * 512 + (k0) + chs * 8,                       \
                  (char*)Adst + li * 16);                                      \
      gload_lds16(Bt + (size_t)(n0 + row) * 512 + (k0) + chs * 8,              \
                  (char*)Bdst + li * 16);                                      \
    }                                                                          \
  }

  STAGEG(0, 0);
  for (int t = 0; t < 8; ++t) {
    if (t < 7) {
      STAGEG((t + 1) & 1, (t + 1) * 64);
      asm volatile("s_waitcnt vmcnt(8)" ::: "memory");   // tile t landed; t+1 in flight
    } else {
      asm volatile("s_waitcnt vmcnt(0)" ::: "memory");
    }
    __builtin_amdgcn_s_barrier();
    __builtin_amdgcn_sched_barrier(0);
    const bf16* Ap = sm + (t & 1) * 32768;
    const bf16* Bp = Ap + 16384;
#pragma unroll
    for (int ks = 0; ks < 2; ++ks) {
      short8 a[8], b[4];
#pragma unroll
      for (int fi = 0; fi < 8; ++fi) {
        int ra = wr * 128 + fi * 16 + l15;
        a[fi] = *(const short8*)&Ap[ra * 64 + (((ks * 4 + l4) ^ (ra & 7)) << 3)];
      }
#pragma unroll
      for (int fj = 0; fj < 4; ++fj) {
        int rb = wcn * 64 + fj * 16 + l15;
        b[fj] = *(const short8*)&Bp[rb * 64 + (((ks * 4 + l4) ^ (rb & 7)) << 3)];
      }
      __builtin_amdgcn_s_setprio(1);
#pragma unroll
      for (int fi = 0; fi < 8; ++fi)
#pragma unroll
        for (int fj = 0; fj < 4; ++fj)
          acc[fi][fj] = mfma16(a[fi], b[fj], acc[fi][fj]);
      __builtin_amdgcn_s_setprio(0);
    }
    __builtin_amdgcn_sched_barrier(0);
    __builtin_amdgcn_s_barrier();
  }
#undef STAGEG

  if (EPI == 0) {
#pragma unroll
    for (int fi = 0; fi < 8; ++fi)
#pragma unroll
      for (int fj = 0; fj < 4; ++fj) {
        int o = n0 + wcn * 64 + fj * 16 + l15;
        float bia = bias[o];
        int part = o >> 9;
        int c = o & 511;
        bf16* dst = part == 0 ? qb : (part == 1 ? kb : vb);
#pragma unroll
        for (int r = 0; r < 4; ++r) {
          size_t m = m0 + wr * 128 + fi * 16 + l4 * 4 + r;
          int bidx = (int)(m >> 13);
          int n = (int)(m & 8191);
          int blk = n >> 5, s = n & 31;
          size_t di = (((size_t)(bidx * 32 + s) * 256 + blk) << 9) | c;
          dst[di] = __float2bfloat16(acc[fi][fj][r] + bia);
        }
      }
  } else {
#pragma unroll
    for (int fi = 0; fi < 8; ++fi)
#pragma unroll
      for (int fj = 0; fj < 4; ++fj) {
        int o = n0 + wcn * 64 + fj * 16 + l15;
        float bia = bias[o];
#pragma unroll
        for (int r = 0; r < 4; ++r) {
          size_t m = m0 + wr * 128 + fi * 16 + l4 * 4 + r;
          outf[m * 512 + o] = acc[fi][fj][r] + bia;
        }
      }
  }
}

// ---------------- v transpose: v[b][s][j][c] -> vT[b][s][c][j] ----------------
__global__ __launch_bounds__(256) void k_transpose_v(const bf16* __restrict__ v,
                                                     bf16* __restrict__ vT) {
  __shared__ bf16 t[32][36];
  int bs = blockIdx.x, j0 = blockIdx.y * 32, c0 = blockIdx.z * 32;
  const bf16* src = v + (size_t)bs * NB * C_;
  bf16* dst = vT + (size_t)bs * C_ * NB;
  int r = threadIdx.x >> 3, c4 = (threadIdx.x & 7) * 4;
  *(ushort4*)&t[r][c4] = *(const ushort4*)(src + (size_t)(j0 + r) * C_ + c0 + c4);
  __syncthreads();
  union { ushort4 u; bf16 b[4]; } o;
  o.b[0] = t[c4 + 0][r]; o.b[1] = t[c4 + 1][r];
  o.b[2] = t[c4 + 2][r]; o.b[3] = t[c4 + 3][r];
  *(ushort4*)(dst + (size_t)(c0 + r) * NB + j0 + c4) = o.u;
}

// ---------------- banded block attention ----------------
// 1D grid 2048; XCD-chunked so consecutive blocks on one XCD walk i-tiles of
// the SAME (b,s) -> sliding K/V band stays L2-resident.
__global__ __launch_bounds__(256) void k_attn(const bf16* __restrict__ qg,
                                              const bf16* __restrict__ kg,
                                              const bf16* __restrict__ vTg,
                                              bf16* __restrict__ outb) {
  __shared__ bf16 Qs[32][520];    // padded: 1040B rows -> 2-way banks only
  __shared__ float Ss[32][164];
  __shared__ bf16 Ps[32][168];
  __shared__ float rowsum[32];
  const int tid = threadIdx.x, lane = tid & 63, wid = tid >> 6;
  const int l15 = lane & 15, l4 = lane >> 4;
  const int gt = (blockIdx.x & 7) * 256 + (blockIdx.x >> 3);
  const int bs = gt >> 3;
  const int b = bs >> 5, s = bs & 31;
  const int i0 = (gt & 7) * 32;
  const int jlo = max(0, i0 - WIN);
  const int jhi = min(NB - 1, i0 + 31 + WIN);
  const int L = jhi - jlo + 1;
  const int nch16 = (L + 15) >> 4, L16 = nch16 << 4;
  const int nch32 = (L16 + 31) >> 5, L32 = nch32 << 5;
  const bf16* Qb = qg + (size_t)bs * NB * C_;
  const bf16* Kb = kg + (size_t)bs * NB * C_;
  const bf16* Vb = vTg + (size_t)bs * C_ * NB;

  // stage Q (32 x 512)
#pragma unroll
  for (int qq = 0; qq < 8; ++qq) {
    int li = qq * 256 + tid;
    int row = li >> 6, ch = li & 63;
    *(float4*)&Qs[row][ch * 8] = *(const float4*)(Qb + (size_t)(i0 + row) * C_ + ch * 8);
  }
  __syncthreads();

  // phase 1: S = scale * Q K^T over the j band
  for (int jc = wid; jc < nch16; jc += 4) {
    f32x4 acc0 = (f32x4){0.f, 0.f, 0.f, 0.f};
    f32x4 acc1 = acc0;
    int jg = jlo + jc * 16 + l15;
    int jcl = min(jg, NB - 1);                 // clamp; masked later
    const bf16* kp = Kb + (size_t)jcl * C_ + l4 * 8;
    const bf16* q0 = &Qs[l15][l4 * 8];
    const bf16* q1 = &Qs[16 + l15][l4 * 8];
#pragma unroll
    for (int cc = 0; cc < 16; ++cc) {
      short8 bfr = *(const short8*)(kp + cc * 32);
      short8 a0 = *(const short8*)(q0 + cc * 32);
      short8 a1 = *(const short8*)(q1 + cc * 32);
      acc0 = mfma16(a0, bfr, acc0);
      acc1 = mfma16(a1, bfr, acc1);
    }
#pragma unroll
    for (int r = 0; r < 4; ++r) {
      Ss[l4 * 4 + r][jc * 16 + l15] = acc0[r] * 0.125f;
      Ss[16 + l4 * 4 + r][jc * 16 + l15] = acc1[r] * 0.125f;
    }
  }
  __syncthreads();

  // phase 2: masked softmax per row (8 lanes per row)
  {
    int row = tid >> 3, u = tid & 7;
    int i = i0 + row;
    int vlo = max(i - WIN, 0), vhi = min(i + WIN, NB - 1);
    float m = -1e30f;
    for (int jj = u; jj < L16; jj += 8) {
      int jg = jlo + jj;
      if (jg >= vlo && jg <= vhi) m = fmaxf(m, Ss[row][jj]);
    }
    m = fmaxf(m, __shfl_xor(m, 1));
    m = fmaxf(m, __shfl_xor(m, 2));
    m = fmaxf(m, __shfl_xor(m, 4));
    float sum = 0.f;
    for (int jj = u; jj < L32; jj += 8) {
      float p = 0.f;
      int jg = jlo + jj;
      if (jj < L16 && jg >= vlo && jg <= vhi) p = __expf(Ss[row][jj] - m);
      sum += p;
      Ps[row][jj] = __float2bfloat16(p);   // unnormalized; pad region = 0
    }
    sum += __shfl_xor(sum, 1);
    sum += __shfl_xor(sum, 2);
    sum += __shfl_xor(sum, 4);
    if (u == 0) rowsum[row] = sum;
  }
  __syncthreads();

  // phase 3: O = (P/rowsum) V  ; wave owns 128 channels
  {
    const int c0 = wid * 128;
#pragma unroll
    for (int ic = 0; ic < 2; ++ic) {
#pragma unroll
      for (int f = 0; f < 8; ++f) {
        f32x4 acc = (f32x4){0.f, 0.f, 0.f, 0.f};
        int c = c0 + f * 16 + l15;
        const bf16* pr = &Ps[ic * 16 + l15][l4 * 8];
        for (int j32 = 0; j32 < nch32; ++j32) {
          int jg = jlo + j32 * 32 + l4 * 8;
          int jcl = (jg <= NB - 8) ? jg : 0;   // whole 8-chunk OOB -> P=0 covers
          short8 a = *(const short8*)(pr + j32 * 32);
          short8 bfr = *(const short8*)(Vb + (size_t)c * NB + jcl);
          acc = mfma16(a, bfr, acc);
        }
#pragma unroll
        for (int r = 0; r < 4; ++r) {
          int il = ic * 16 + l4 * 4 + r;
          float val = acc[r] / rowsum[il];
          int n = (i0 + il) * 32 + s;
          outb[((size_t)b * N_ + n) * C_ + c] = __float2bfloat16(val);
        }
      }
    }
  }
}

// ---------------- launch ----------------
extern "C" void kernel_launch(void* const* d_in, const int* in_sizes, int n_in,
                              void* d_out, int out_size, void* d_ws, size_t ws_size,
                              hipStream_t stream) {
  const float* x = (const float*)d_in[0];
  const float* Wqkv = (const float*)d_in[1];
  const float* bqkv = (const float*)d_in[2];
  const float* Wproj = (const float*)d_in[3];
  const float* bproj = (const float*)d_in[4];

  char* ws = (char*)d_ws;
  const size_t SLOT = 67108864ull;           // 64 MiB (33.5M bf16)
  bf16* slotA = (bf16*)ws;                   // xb, then vT
  bf16* slotB = (bf16*)(ws + SLOT);          // v, then attn_out
  bf16* Wqkv_t = (bf16*)(ws + 2 * SLOT);
  bf16* Wproj_t = (bf16*)(ws + 2 * SLOT + 1572864);
  float* bias_perm = (float*)(ws + 2 * SLOT + 1572864 + 524288);
  bf16* qbuf = (bf16*)d_out;                 // q,k scratch inside d_out (dead before proj writes)
  bf16* kbuf = qbuf + 33554432ull;

  static int attr_done = 0;
  if (!attr_done) {
    hipFuncSetAttribute((const void*)k_gemm<0>,
                        hipFuncAttributeMaxDynamicSharedMemorySize, 131072);
    hipFuncSetAttribute((const void*)k_gemm<1>,
                        hipFuncAttributeMaxDynamicSharedMemorySize, 131072);
    attr_done = 1;
  }

  k_conv_x<<<32768, 256, 0, stream>>>((const float4*)x, (ushort4*)slotA);
  k_conv_wqkv<<<1536, 256, 0, stream>>>(Wqkv, bqkv, Wqkv_t, bias_perm);
  k_conv_wproj<<<512, 256, 0, stream>>>(Wproj, Wproj_t);

  // qkv projection: A=xb, Bt=Wqkv_t -> q,k (d_out), v (slotB)
  k_gemm<0><<<256 * 6, 512, 131072, stream>>>(slotA, Wqkv_t, bias_perm,
                                              qbuf, kbuf, slotB, nullptr, 6);
  // v -> vT (slotA; xb dead)
  k_transpose_v<<<dim3(256, 8, 16), 256, 0, stream>>>(slotB, slotA);
  // attention -> attn_out (slotB; v dead)
  k_attn<<<2048, 256, 0, stream>>>(qbuf, kbuf, slotA, slotB);
  // proj: A=attn_out, Bt=Wproj_t -> d_out f32 (q,k dead)
  k_gemm<1><<<256 * 2, 512, 131072, stream>>>(slotB, Wproj_t, bproj,
                                              nullptr, nullptr, nullptr, (float*)d_out, 2);
}